// Round 6
// baseline (871.533 us; speedup 1.0000x reference)
//
#include <hip/hip_runtime.h>
#include <float.h>

#define N_ROWS 65536
#define D_IN   128
#define DH     64
#define K_CB   2048

typedef const __attribute__((address_space(1))) void* gas_p;
typedef __attribute__((address_space(3))) void* las_p;
typedef _Float16 f16x8 __attribute__((ext_vector_type(8)));
typedef float    f32x4 __attribute__((ext_vector_type(4)));

// ---------------- K_prep ---------------------------------------------------
// blocks 0..127: emb -> epl (2-plane fp16 split, 16B-chunk swizzled) + e2.
// block 128: W -> wfrag: B-fragment-linear 2-plane split of W^T so k_main can
// load projection B-frags as single coalesced 16B/lane reads.
__global__ __launch_bounds__(256) void k_prep(
    const float* __restrict__ emb, const float* __restrict__ W,
    const float* __restrict__ b,
    _Float16* __restrict__ epl,    // [2][K_CB][64] swizzled
    float* __restrict__ e2,        // [K_CB]
    _Float16* __restrict__ wfrag) {// [2][4ks][4nt][64lane][8e]
  int tid = threadIdx.x;
  if (blockIdx.x == 128) {
    for (int g = tid; g < 8192; g += 256) {
      int e = g & 7, lane = (g >> 3) & 63, nt = (g >> 9) & 3, ks = (g >> 11) & 3;
      int k = ks * 32 + (lane >> 4) * 8 + e;     // B-frag: k-span by quad
      int j = nt * 16 + (lane & 15);             // B-frag: col = l16
      float v = W[j * 128 + k];
      _Float16 h = (_Float16)v;
      _Float16 m = (_Float16)(v - (float)h);
      int idx = ((ks * 4 + nt) * 64 + lane) * 8 + e;
      wfrag[idx]        = h;
      wfrag[8192 + idx] = m;
    }
    return;
  }
  __shared__ __align__(16) float Wl[64 * 140];
  __shared__ __align__(16) float Zl[16 * 128];
  int n0 = blockIdx.x * 16;
  const size_t plane = (size_t)K_CB * 64;

#pragma unroll
  for (int i = 0; i < 8; ++i) {
    int idx4 = tid + 256 * i;
    int j = idx4 >> 5;
    int d4 = (idx4 & 31) * 4;
    *(float4*)&Wl[j * 140 + d4] = *(const float4*)(W + j * 128 + d4);
  }
#pragma unroll
  for (int i = 0; i < 2; ++i) {
    int idx4 = tid + 256 * i;
    int r = idx4 >> 5;
    int d4 = (idx4 & 31) * 4;
    *(float4*)&Zl[r * 128 + d4] = *(const float4*)(emb + (size_t)(n0 + r) * 128 + d4);
  }
  int j = tid & 63, g = tid >> 6;
  float bj = b[j];
  __syncthreads();

  float acc[4] = {0.f, 0.f, 0.f, 0.f};
  for (int d4 = 0; d4 < 128; d4 += 4) {
    float4 w4 = *(float4*)&Wl[j * 140 + d4];
#pragma unroll
    for (int i = 0; i < 4; ++i) {
      float4 z4 = *(float4*)&Zl[(g * 4 + i) * 128 + d4];
      acc[i] = fmaf(z4.x, w4.x, fmaf(z4.y, w4.y, fmaf(z4.z, w4.z, fmaf(z4.w, w4.w, acc[i]))));
    }
  }
#pragma unroll
  for (int i = 0; i < 4; ++i) {
    int n = n0 + g * 4 + i;
    float v = acc[i] + bj;
    _Float16 h = (_Float16)v;  float rm = v - (float)h;
    _Float16 m = (_Float16)rm;
    int pos = (((j >> 3) ^ (n & 7)) << 3) | (j & 7);
    size_t base = (size_t)n * 64 + pos;
    epl[base]         = h;
    epl[plane + base] = m;
    float s = v * v;
#pragma unroll
    for (int off = 32; off > 0; off >>= 1) s += __shfl_xor(s, off, 64);
    if (j == 0) e2[n] = s;
  }
}

// ---------------- K_main: fully fused --------------------------------------
// 1024 blocks x 64 z-rows. Phase 1: stage raw Z (coalesced, chunk-swizzled
// source), project via 2-plane fp16 MFMA (B-frags from wfrag, L2-hot), split
// into swizzled Zs, hoist score A-frags to registers. Phase 2: 32 K-tiles of
// 64 cols, 3-deep LDS buffers, raw s_barrier + counted vmcnt(8) so OH-zero NT
// stores and next-tile staging stay in flight (never drained in-loop).
__global__ __launch_bounds__(256, 2) void k_main(
    const float* __restrict__ Z,
    const float* __restrict__ b,
    const _Float16* __restrict__ epl,   // [2][K_CB][64] swizzled
    const _Float16* __restrict__ wfrag, // [2][4][4][64][8]
    const float* __restrict__ e2,       // [K_CB]
    const float* __restrict__ emb,      // [K_CB][128]
    float* __restrict__ outQ,
    float* __restrict__ outOH) {
  __shared__ __align__(16) char U[49152];  // phase1: Zraw 32K | phase2: es[3] x 16K
  int tid = threadIdx.x, lane = tid & 63, wid = tid >> 6;
  int quad = lane >> 4, l16 = lane & 15;
  int row0 = blockIdx.x * 64;

  // ---- stage Zraw [64][128] fp32, 16B-chunk source-swizzle (slot p <- chunk p^(r&7))
  for (int q2 = wid; q2 < 32; q2 += 4) {
    int L = q2 * 1024 + lane * 16;
    int r = L >> 9;
    int pslot = (L >> 4) & 31;
    const char* g = (const char*)(Z + (size_t)(row0 + r) * 128) + ((pslot ^ (r & 7)) * 16);
    __builtin_amdgcn_global_load_lds((gas_p)g, (las_p)(U + q2 * 1024), 16, 0, 0);
  }

  // e2 + bias to registers (latency hidden under staging; drained at barrier)
  float e2r[32];
#pragma unroll
  for (int t = 0; t < 32; ++t) e2r[t] = e2[t * 64 + wid * 16 + l16];
  float bjr[4];
#pragma unroll
  for (int nt = 0; nt < 4; ++nt) bjr[nt] = b[nt * 16 + l16];

  __syncthreads();                          // Zraw ready

  // ---- projection: wave w computes z_ rows w*16..+16 x 64 cols via MFMA ----
  const float* Zraw = (const float*)U;
  const f16x8* wf = (const f16x8*)wfrag;
  f32x4 pacc[4];
#pragma unroll
  for (int nt = 0; nt < 4; ++nt) pacc[nt] = (f32x4){0.f, 0.f, 0.f, 0.f};
  int zrow = wid * 16 + l16;                // A-frag row = l16
#pragma unroll
  for (int ks = 0; ks < 4; ++ks) {
    int c0 = ks * 8 + quad * 2;             // A-frag k-span: quad*8
    f32x4 v0 = *(const f32x4*)(Zraw + zrow * 128 + ((c0 ^ (zrow & 7)) * 4));
    f32x4 v1 = *(const f32x4*)(Zraw + zrow * 128 + (((c0 + 1) ^ (zrow & 7)) * 4));
    f16x8 Ah, Am;
#pragma unroll
    for (int e = 0; e < 4; ++e) {
      _Float16 h0 = (_Float16)v0[e];
      Ah[e] = h0;  Am[e] = (_Float16)(v0[e] - (float)h0);
      _Float16 h1 = (_Float16)v1[e];
      Ah[e + 4] = h1;  Am[e + 4] = (_Float16)(v1[e] - (float)h1);
    }
#pragma unroll
    for (int nt = 0; nt < 4; ++nt) {
      f16x8 Bh = wf[(ks * 4 + nt) * 64 + lane];
      f16x8 Bm = wf[1024 + (ks * 4 + nt) * 64 + lane];
      f32x4 c = pacc[nt];
      c = __builtin_amdgcn_mfma_f32_16x16x32_f16(Am, Bm, c, 0, 0, 0); // mm
      c = __builtin_amdgcn_mfma_f32_16x16x32_f16(Am, Bh, c, 0, 0, 0); // mh
      c = __builtin_amdgcn_mfma_f32_16x16x32_f16(Ah, Bm, c, 0, 0, 0); // hm
      c = __builtin_amdgcn_mfma_f32_16x16x32_f16(Ah, Bh, c, 0, 0, 0); // hh
      pacc[nt] = c;
    }
  }
  __syncthreads();                          // all Zraw reads done -> [0,16K) free

  // ---- split z_ + bias -> 2-plane swizzled Zs at U[0,16K) ----
  _Float16* Zs = (_Float16*)U;
#pragma unroll
  for (int nt = 0; nt < 4; ++nt) {
    int j = nt * 16 + l16;                  // C: col = l16
#pragma unroll
    for (int r = 0; r < 4; ++r) {
      int row = wid * 16 + quad * 4 + r;    // C: row = quad*4 + reg
      float v = pacc[nt][r] + bjr[nt];
      _Float16 h = (_Float16)v;
      _Float16 m = (_Float16)(v - (float)h);
      int pos = (((j >> 3) ^ (row & 7)) << 3) | (j & 7);
      Zs[row * 64 + pos]        = h;
      Zs[4096 + row * 64 + pos] = m;
    }
  }
  __syncthreads();                          // Zs complete

  // ---- score A-fragments to registers (invariant across all K-tiles) ----
  f16x8 A[2][4][2];
#pragma unroll
  for (int step = 0; step < 2; ++step)
#pragma unroll
    for (int mt = 0; mt < 4; ++mt) {
      int tr = mt * 16 + l16;
      int cph = (step * 4 + quad) ^ (tr & 7);
      const _Float16* pa = Zs + tr * 64 + cph * 8;
      A[step][mt][0] = *(const f16x8*)pa;
      A[step][mt][1] = *(const f16x8*)(pa + 4096);
    }
  __syncthreads();                          // A reads done -> whole U free

  // ---- stage tile 0 -> es[0] = U[0,16K) ----
  for (int q = wid; q < 16; q += 4) {
    int p = q >> 3, within = (q & 7) * 1024;
    const char* g = (const char*)epl + (size_t)p * (K_CB * 128) + within + lane * 16;
    __builtin_amdgcn_global_load_lds((gas_p)g, (las_p)(U + p * 8192 + within), 16, 0, 0);
  }

  float best[16]; int bidx[16];
#pragma unroll
  for (int s = 0; s < 16; ++s) { best[s] = FLT_MAX; bidx[s] = 0; }
  float* ohbase = outOH + (size_t)row0 * K_CB;

  // ---- main loop: per tile issue {4 loads, 4 NT stores}, wait vmcnt(8)
  // (drains prev tile's loads+stores, keeps current in flight), s_barrier,
  // compute. 3 buffers make stage-ahead race-free.
#pragma unroll
  for (int t = 0; t < 32; ++t) {
    if (t < 31) {
      char* esn = U + ((t + 1) % 3) * 16384;
      for (int q = wid; q < 16; q += 4) {
        int p = q >> 3, within = (q & 7) * 1024;
        const char* g = (const char*)epl + (size_t)p * (K_CB * 128)
                      + (size_t)(t + 1) * 8192 + within + lane * 16;
        __builtin_amdgcn_global_load_lds((gas_p)g, (las_p)(esn + p * 8192 + within), 16, 0, 0);
      }
    }
    {   // one_hot zero chunk t: 16KB of this block's contiguous 512KB region
      f32x4 zz = (f32x4){0.f, 0.f, 0.f, 0.f};
#pragma unroll
      for (int s = 0; s < 4; ++s)
        __builtin_nontemporal_store(zz, (f32x4*)(ohbase + t * 4096) + tid + 256 * s);
    }
    if (t < 31) { asm volatile("s_waitcnt vmcnt(8)" ::: "memory"); }
    else        { asm volatile("s_waitcnt vmcnt(4)" ::: "memory"); }
    __builtin_amdgcn_sched_barrier(0);
    __builtin_amdgcn_s_barrier();
    __builtin_amdgcn_sched_barrier(0);

    const _Float16* esc = (const _Float16*)(U + (t % 3) * 16384);
    f32x4 accf[4];
#pragma unroll
    for (int mt = 0; mt < 4; ++mt) accf[mt] = (f32x4){0.f, 0.f, 0.f, 0.f};

#pragma unroll
    for (int step = 0; step < 2; ++step) {
      int tc = wid * 16 + l16;
      int cph = (step * 4 + quad) ^ (l16 & 7);
      const _Float16* pb = esc + tc * 64 + cph * 8;
      f16x8 Bh = *(const f16x8*)pb;
      f16x8 Bm = *(const f16x8*)(pb + 4096);
#pragma unroll
      for (int mt = 0; mt < 4; ++mt) {
        f32x4 c = accf[mt];
        c = __builtin_amdgcn_mfma_f32_16x16x32_f16(A[step][mt][1], Bm, c, 0, 0, 0); // mm
        c = __builtin_amdgcn_mfma_f32_16x16x32_f16(A[step][mt][1], Bh, c, 0, 0, 0); // mh
        c = __builtin_amdgcn_mfma_f32_16x16x32_f16(A[step][mt][0], Bm, c, 0, 0, 0); // hm
        c = __builtin_amdgcn_mfma_f32_16x16x32_f16(A[step][mt][0], Bh, c, 0, 0, 0); // hh
        accf[mt] = c;
      }
    }

    int col = t * 64 + wid * 16 + l16;
    float ev = e2r[t];
#pragma unroll
    for (int mt = 0; mt < 4; ++mt)
#pragma unroll
      for (int r = 0; r < 4; ++r) {
        float s = fmaf(-2.0f, accf[mt][r], ev);
        int slot = mt * 4 + r;
        if (s < best[slot]) { best[slot] = s; bidx[slot] = col; }
      }
  }
  __syncthreads();                          // drains remaining stores + loads

  // ---- cross-lane argmin reduction: 64 rows x 64 slots ----
  float* redm = (float*)U;                  // [64][64]
  int*   redi = (int*)(U + 16384);          // [64][64]
#pragma unroll
  for (int mt = 0; mt < 4; ++mt)
#pragma unroll
    for (int r = 0; r < 4; ++r) {
      int row = mt * 16 + quad * 4 + r;
      redm[row * 64 + wid * 16 + l16] = best[mt * 4 + r];
      redi[row * 64 + wid * 16 + l16] = bidx[mt * 4 + r];
    }
  __syncthreads();
  int* cidx = (int*)(U + 32768);
  if (tid < 64) {
    float m = redm[tid * 64]; int mi = redi[tid * 64];
    for (int s = 1; s < 64; ++s) {
      float v = redm[tid * 64 + s]; int vi = redi[tid * 64 + s];
      if (v < m || (v == m && vi < mi)) { m = v; mi = vi; }
    }
    cidx[tid] = mi;
  }
  __syncthreads();                          // zeros acked; cidx visible

  if (tid < 64) outOH[(size_t)(row0 + tid) * K_CB + cidx[tid]] = 1.0f;

  // quantized gather (emb L2-hot); NT stores keep L2 for epl
#pragma unroll
  for (int i = 0; i < 8; ++i) {
    int idx = tid + 256 * i;
    int r = idx >> 5, c = (idx & 31) * 4;
    f32x4 v = *(const f32x4*)(emb + (size_t)cidx[r] * D_IN + c);
    __builtin_nontemporal_store(v, (f32x4*)(outQ + (size_t)(row0 + r) * D_IN + c));
  }
}

extern "C" void kernel_launch(void* const* d_in, const int* in_sizes, int n_in,
                              void* d_out, int out_size, void* d_ws, size_t ws_size,
                              hipStream_t stream) {
  (void)in_sizes; (void)n_in; (void)out_size; (void)ws_size;
  const float* Z   = (const float*)d_in[0];
  const float* W   = (const float*)d_in[1];
  const float* b   = (const float*)d_in[2];
  const float* emb = (const float*)d_in[3];
  float* outQ  = (float*)d_out;
  float* outOH = (float*)d_out + (size_t)N_ROWS * D_IN;

  // ws layout (bytes): epl 524288 | e2 8192 | wfrag 32768  (total 565248)
  char* wsb = (char*)d_ws;
  _Float16* epl   = (_Float16*)wsb;
  float*    e2    = (float*)(wsb + 524288);
  _Float16* wfrag = (_Float16*)(wsb + 532480);

  k_prep<<<129, 256, 0, stream>>>(emb, W, b, epl, e2, wfrag);
  k_main<<<1024, 256, 0, stream>>>(Z, b, epl, wfrag, e2, emb, outQ, outOH);
}